// Round 8
// baseline (380.739 us; speedup 1.0000x reference)
//
#include <hip/hip_runtime.h>
#include <hip/hip_bf16.h>

#define NHEAD 8
#define CDIM 12
#define DMODEL 96
#define NBLK 128        // blocks in the counting-sort pass

typedef __attribute__((ext_vector_type(8))) short bf16x8;
typedef __attribute__((ext_vector_type(4))) float f32x4;

__device__ __forceinline__ unsigned short f2bf(float f) {
    unsigned int u = __float_as_uint(f);
    unsigned int r = (u + 0x7fffu + ((u >> 16) & 1u)) >> 16;   // RNE
    return (unsigned short)r;
}

// ---------------- W -> transposed split-bf16 (tiny, once) ----------------
__global__ void cvt_w_kernel(const float* __restrict__ W,   // [K][96]
                             unsigned short* __restrict__ Wth,
                             unsigned short* __restrict__ Wtl, int K)
{
    int idx = blockIdx.x * 256 + threadIdx.x;   // flat c*K + k
    if (idx >= 96 * K) return;
    int c = idx / K, k = idx - c * K;
    float f = W[k * 96 + c];
    unsigned short h = f2bf(f);
    float hf = __uint_as_float((unsigned int)h << 16);
    Wth[idx] = h;
    Wtl[idx] = f2bf(f - hf);
}

// ---------------- MFMA GEMM + fused attention coefficients ----------------
// H[N,96] = X[N,K] @ W[K,96] via split-bf16 (xh*wh + xl*wh + xh*wl).
// 256 thr = 4 waves; wave w computes rows n0+16w..+15 x all 96 cols
// (6 16x16 tiles). A-frag: row=lane&15, k=8*(lane>>4)+j (packed on the fly
// from fp32). B-frag from Wt[96][K] bf16: 16B contiguous per lane.
// D: col=lane&15, row=4*(lane>>4)+j. No LDS staging, no k-loop barriers.
template<int K>
__global__ __launch_bounds__(256) void gemm_mfma_att(
    const float* __restrict__ X,
    const unsigned short* __restrict__ Wth,
    const unsigned short* __restrict__ Wtl,
    const float* __restrict__ att_s, const float* __restrict__ att_d,
    float* __restrict__ H, float* __restrict__ a_s, float* __restrict__ a_d,
    int N)
{
    constexpr int NKC = K / 32;
    __shared__ float redS[64][8];
    __shared__ float redD[64][8];
    const int t = threadIdx.x;
    const int w = t >> 6;
    const int lane = t & 63;
    const int l16 = lane & 15, lhi = lane >> 4;
    const int n0 = blockIdx.x * 64;
    const int growA = n0 + 16 * w + l16;              // A-frag row
    const int growC = (growA < N) ? growA : (N - 1);  // clamped for loads

    for (int e = t; e < 512; e += 256) {
        ((float*)redS)[e] = 0.f;
        ((float*)redD)[e] = 0.f;
    }

    f32x4 acc[6];
#pragma unroll
    for (int ct = 0; ct < 6; ++ct) acc[ct] = (f32x4){0.f, 0.f, 0.f, 0.f};

    const float* xrow = X + (size_t)growC * K;

#pragma unroll
    for (int kc = 0; kc < NKC; ++kc) {
        const int kb = kc * 32 + lhi * 8;
        float4 xa = *(const float4*)(xrow + kb);
        float4 xb = *(const float4*)(xrow + kb + 4);
        float xv[8] = {xa.x, xa.y, xa.z, xa.w, xb.x, xb.y, xb.z, xb.w};
        bf16x8 ah, al;
#pragma unroll
        for (int j = 0; j < 8; ++j) {
            unsigned short h = f2bf(xv[j]);
            float hf = __uint_as_float((unsigned int)h << 16);
            ah[j] = (short)h;
            al[j] = (short)f2bf(xv[j] - hf);
        }
#pragma unroll
        for (int ct = 0; ct < 6; ++ct) {
            const int col = ct * 16 + l16;
            bf16x8 bh = *(const bf16x8*)(Wth + (size_t)col * K + kb);
            bf16x8 bl = *(const bf16x8*)(Wtl + (size_t)col * K + kb);
            acc[ct] = __builtin_amdgcn_mfma_f32_16x16x32_bf16(ah, bh, acc[ct], 0, 0, 0);
            acc[ct] = __builtin_amdgcn_mfma_f32_16x16x32_bf16(al, bh, acc[ct], 0, 0, 0);
            acc[ct] = __builtin_amdgcn_mfma_f32_16x16x32_bf16(ah, bl, acc[ct], 0, 0, 0);
        }
    }

    // epilogue: store H + fused att partials (LDS atomics)
    const int orowL = 16 * w + lhi * 4;
#pragma unroll
    for (int ct = 0; ct < 6; ++ct) {
        const int c = ct * 16 + l16;
        const float as_c = att_s[c];
        const float ad_c = att_d[c];
        const int hh = c / CDIM;
#pragma unroll
        for (int j = 0; j < 4; ++j) {
            float v = acc[ct][j];
            int rL = orowL + j;
            int gr = n0 + rL;
            if (gr < N) H[(size_t)gr * 96 + c] = v;
            atomicAdd(&redS[rL][hh], v * as_c);
            atomicAdd(&redD[rL][hh], v * ad_c);
        }
    }
    __syncthreads();
    for (int e = t; e < 512; e += 256) {
        int rL = e >> 3, hh = e & 7;
        int gr = n0 + rL;
        if (gr < N) {
            a_s[gr * NHEAD + hh] = redS[rL][hh];
            a_d[gr * NHEAD + hh] = redD[rL][hh];
        }
    }
}

// ---------------- CSR build: two-level counting sort, no global atomics ----
__global__ __launch_bounds__(1024) void hist2d_kernel(
    const int* __restrict__ dsti, int* __restrict__ hist2d,
    int E0, int Etot, int nbins)
{
    __shared__ int hist[1024];
    const int t = threadIdx.x, b = blockIdx.x;
    hist[t] = 0;
    __syncthreads();
    const int chunk = (Etot + NBLK - 1) / NBLK;
    const int e0 = b * chunk;
    const int e1 = (e0 + chunk < Etot) ? e0 + chunk : Etot;
    for (int e = e0 + t; e < e1; e += 1024) {
        int d = (e < E0) ? dsti[e] : e - E0;
        atomicAdd(&hist[d >> 6], 1);
    }
    __syncthreads();
    if (t < nbins) hist2d[(size_t)t * NBLK + b] = hist[t];
}

__global__ __launch_bounds__(1024) void place_kernel(
    const int* __restrict__ srci, const int* __restrict__ dsti,
    const int* __restrict__ sc2d, int2* __restrict__ rec,
    int E0, int Etot)
{
    __shared__ int run[1024];
    const int t = threadIdx.x, b = blockIdx.x;
    run[t] = 0;
    __syncthreads();
    const int chunk = (Etot + NBLK - 1) / NBLK;
    const int e0 = b * chunk;
    const int e1 = (e0 + chunk < Etot) ? e0 + chunk : Etot;
    for (int e = e0 + t; e < e1; e += 1024) {
        int s, d;
        if (e < E0) { s = srci[e]; d = dsti[e]; }
        else        { s = d = e - E0; }
        int bin = d >> 6;
        int r = atomicAdd(&run[bin], 1);
        rec[(size_t)sc2d[bin * NBLK + b] + r] = make_int2(d, s);
    }
}

__global__ __launch_bounds__(256) void bucketDeg_kernel(
    const int* __restrict__ sc2d, const int2* __restrict__ rec,
    int* __restrict__ deg, int N)
{
    __shared__ int deg64[64];
    const int t = threadIdx.x, b = blockIdx.x;
    if (t < 64) deg64[t] = 0;
    __syncthreads();
    const int r0 = sc2d[b * NBLK], r1 = sc2d[(b + 1) * NBLK];
    for (int i = r0 + t; i < r1; i += 256)
        atomicAdd(&deg64[rec[i].x & 63], 1);
    __syncthreads();
    const int gn = b * 64 + t;
    if (t < 64 && gn < N) deg[gn] = deg64[t];
}

__global__ __launch_bounds__(256) void bucketC_kernel(
    const int* __restrict__ sc2d, const int2* __restrict__ rec,
    const int* __restrict__ rowptr, int* __restrict__ col)
{
    __shared__ int run64[64];
    const int t = threadIdx.x, b = blockIdx.x;
    if (t < 64) run64[t] = 0;
    __syncthreads();
    const int r0 = sc2d[b * NBLK], r1 = sc2d[(b + 1) * NBLK];
    for (int i = r0 + t; i < r1; i += 256) {
        int2 v = rec[i];
        int rank = atomicAdd(&run64[v.x & 63], 1);
        col[rowptr[v.x] + rank] = v.y;
    }
}

// ---------------- generic scan chain (exclusive) ----------------
__global__ __launch_bounds__(1024) void scan_block_kernel(
    const int* __restrict__ in, int* __restrict__ out,
    int* __restrict__ bsum, int n)
{
    __shared__ int sh[1024];
    int t = threadIdx.x, g = blockIdx.x * 1024 + t;
    int v = (g < n) ? in[g] : 0;
    sh[t] = v;
    __syncthreads();
    for (int off = 1; off < 1024; off <<= 1) {
        int add = (t >= off) ? sh[t - off] : 0;
        __syncthreads();
        sh[t] += add;
        __syncthreads();
    }
    if (g < n) out[g] = sh[t] - v;     // exclusive
    if (t == 1023) bsum[blockIdx.x] = sh[t];
}

__global__ void scan_bsum_kernel(int* bsum, int nb)
{
    if (threadIdx.x == 0) {
        int acc = 0;
        for (int i = 0; i < nb; ++i) { int v = bsum[i]; bsum[i] = acc; acc += v; }
    }
}

__global__ void scan_add_kernel(int* __restrict__ arr, const int* __restrict__ bsum,
                                int n, int total)
{
    int g = blockIdx.x * blockDim.x + threadIdx.x;
    if (g < n) arr[g] += bsum[g >> 10];
    if (g == 0) arr[n] = total;        // sentinel
}

// ---------------- edge pass (CSR): 8-deep pipelined gather ----------------
__global__ __launch_bounds__(384) void edge2_vec_kernel(
    const int* __restrict__ rowptr, const int* __restrict__ col,
    const float* __restrict__ H, const float* __restrict__ a_s,
    const float* __restrict__ a_d, const float* __restrict__ bias,
    float* __restrict__ out, int N)
{
    const int grp  = threadIdx.x / 24;      // 16 nodes/block
    const int lane = threadIdx.x % 24;      // float4 chunk
    const int d = blockIdx.x * 16 + grp;
    if (d >= N) return;
    const int hh = lane / 3;
    const float ad  = a_d[d * NHEAD + hh];
    const float4* __restrict__ H4 = (const float4*)H;

    int j0 = rowptr[d], j1 = rowptr[d + 1];
    float4 acc = make_float4(0.f, 0.f, 0.f, 0.f);
    float den = 1e-16f;
    int j = j0;
    for (; j + 7 < j1; j += 8) {
        int s0 = col[j],   s1 = col[j+1], s2 = col[j+2], s3 = col[j+3];
        int s4 = col[j+4], s5 = col[j+5], s6 = col[j+6], s7 = col[j+7];
        float v0 = a_s[s0 * NHEAD + hh], v1 = a_s[s1 * NHEAD + hh];
        float v2 = a_s[s2 * NHEAD + hh], v3 = a_s[s3 * NHEAD + hh];
        float v4 = a_s[s4 * NHEAD + hh], v5 = a_s[s5 * NHEAD + hh];
        float v6 = a_s[s6 * NHEAD + hh], v7 = a_s[s7 * NHEAD + hh];
        float4 h0 = H4[(size_t)s0 * 24 + lane];
        float4 h1 = H4[(size_t)s1 * 24 + lane];
        float4 h2 = H4[(size_t)s2 * 24 + lane];
        float4 h3 = H4[(size_t)s3 * 24 + lane];
        float4 h4 = H4[(size_t)s4 * 24 + lane];
        float4 h5 = H4[(size_t)s5 * 24 + lane];
        float4 h6 = H4[(size_t)s6 * 24 + lane];
        float4 h7 = H4[(size_t)s7 * 24 + lane];
        v0 += ad; v1 += ad; v2 += ad; v3 += ad;
        v4 += ad; v5 += ad; v6 += ad; v7 += ad;
        v0 = v0 > 0.f ? v0 : 0.2f * v0;  v1 = v1 > 0.f ? v1 : 0.2f * v1;
        v2 = v2 > 0.f ? v2 : 0.2f * v2;  v3 = v3 > 0.f ? v3 : 0.2f * v3;
        v4 = v4 > 0.f ? v4 : 0.2f * v4;  v5 = v5 > 0.f ? v5 : 0.2f * v5;
        v6 = v6 > 0.f ? v6 : 0.2f * v6;  v7 = v7 > 0.f ? v7 : 0.2f * v7;
        float e0 = __expf(v0), e1 = __expf(v1), e2 = __expf(v2), e3 = __expf(v3);
        float e4 = __expf(v4), e5 = __expf(v5), e6 = __expf(v6), e7 = __expf(v7);
        den += e0 + e1 + e2 + e3 + e4 + e5 + e6 + e7;
        acc.x = fmaf(e0, h0.x, acc.x); acc.y = fmaf(e0, h0.y, acc.y);
        acc.z = fmaf(e0, h0.z, acc.z); acc.w = fmaf(e0, h0.w, acc.w);
        acc.x = fmaf(e1, h1.x, acc.x); acc.y = fmaf(e1, h1.y, acc.y);
        acc.z = fmaf(e1, h1.z, acc.z); acc.w = fmaf(e1, h1.w, acc.w);
        acc.x = fmaf(e2, h2.x, acc.x); acc.y = fmaf(e2, h2.y, acc.y);
        acc.z = fmaf(e2, h2.z, acc.z); acc.w = fmaf(e2, h2.w, acc.w);
        acc.x = fmaf(e3, h3.x, acc.x); acc.y = fmaf(e3, h3.y, acc.y);
        acc.z = fmaf(e3, h3.z, acc.z); acc.w = fmaf(e3, h3.w, acc.w);
        acc.x = fmaf(e4, h4.x, acc.x); acc.y = fmaf(e4, h4.y, acc.y);
        acc.z = fmaf(e4, h4.z, acc.z); acc.w = fmaf(e4, h4.w, acc.w);
        acc.x = fmaf(e5, h5.x, acc.x); acc.y = fmaf(e5, h5.y, acc.y);
        acc.z = fmaf(e5, h5.z, acc.z); acc.w = fmaf(e5, h5.w, acc.w);
        acc.x = fmaf(e6, h6.x, acc.x); acc.y = fmaf(e6, h6.y, acc.y);
        acc.z = fmaf(e6, h6.z, acc.z); acc.w = fmaf(e6, h6.w, acc.w);
        acc.x = fmaf(e7, h7.x, acc.x); acc.y = fmaf(e7, h7.y, acc.y);
        acc.z = fmaf(e7, h7.z, acc.z); acc.w = fmaf(e7, h7.w, acc.w);
    }
    for (; j < j1; ++j) {
        int s = col[j];
        float v = a_s[s * NHEAD + hh] + ad;
        v = v > 0.f ? v : 0.2f * v;
        float ex = __expf(v);
        den += ex;
        float4 hv = H4[(size_t)s * 24 + lane];
        acc.x = fmaf(ex, hv.x, acc.x); acc.y = fmaf(ex, hv.y, acc.y);
        acc.z = fmaf(ex, hv.z, acc.z); acc.w = fmaf(ex, hv.w, acc.w);
    }
    float inv = 1.0f / den;
    float4 bv = ((const float4*)bias)[lane];
    float4 o;
    o.x = fmaf(acc.x, inv, bv.x); o.y = fmaf(acc.y, inv, bv.y);
    o.z = fmaf(acc.z, inv, bv.z); o.w = fmaf(acc.w, inv, bv.w);
    o.x = o.x > 0.f ? o.x : 0.f;  o.y = o.y > 0.f ? o.y : 0.f;
    o.z = o.z > 0.f ? o.z : 0.f;  o.w = o.w > 0.f ? o.w : 0.f;
    ((float4*)out)[(size_t)d * 24 + lane] = o;
}

extern "C" void kernel_launch(void* const* d_in, const int* in_sizes, int n_in,
                              void* d_out, int out_size, void* d_ws, size_t ws_size,
                              hipStream_t stream) {
    const float* x   = (const float*)d_in[0];
    const int*   ei  = (const int*)d_in[1];
    const float* W1  = (const float*)d_in[2];
    const float* as1 = (const float*)d_in[3];
    const float* ad1 = (const float*)d_in[4];
    const float* b1  = (const float*)d_in[5];
    const float* W2  = (const float*)d_in[6];
    const float* as2 = (const float*)d_in[7];
    const float* ad2 = (const float*)d_in[8];
    const float* b2  = (const float*)d_in[9];

    const int N    = in_sizes[0] / 128;   // 50000
    const int E0   = in_sizes[1] / 2;     // 800000
    const int Etot = E0 + N;
    const int* srci = ei;
    const int* dsti = ei + E0;
    const int nbins = (N + 63) >> 6;      // 782
    const int M2    = nbins * NBLK;       // 100096

    // -------- workspace layout --------
    char* wsb = (char*)d_ws;
    float* H    = (float*)wsb;            wsb += (size_t)N * DMODEL * 4;
    float* H1   = (float*)wsb;            wsb += (size_t)N * DMODEL * 4;
    float* AS   = (float*)wsb;            wsb += (size_t)N * NHEAD * 4;
    float* AD   = (float*)wsb;            wsb += (size_t)N * NHEAD * 4;
    int* HIST2D = (int*)wsb;              wsb += (size_t)M2 * 4;
    int* SC2D   = (int*)wsb;              wsb += (size_t)(M2 + 1) * 4;
    int* DEG    = (int*)wsb;              wsb += (size_t)N * 4;
    int* ROWPTR = (int*)wsb;              wsb += (size_t)(N + 1) * 4;
    int* BSUM   = (int*)wsb;              wsb += 256 * 4;
    int* COL    = (int*)wsb;              wsb += (size_t)Etot * 4;
    unsigned short* WTH1 = (unsigned short*)wsb; wsb += 96 * 128 * 2;
    unsigned short* WTL1 = (unsigned short*)wsb; wsb += 96 * 128 * 2;
    unsigned short* WTH2 = (unsigned short*)wsb; wsb += 96 * 96 * 2;
    unsigned short* WTL2 = (unsigned short*)wsb; wsb += 96 * 96 * 2;
    wsb = (char*)(((uintptr_t)wsb + 15) & ~(uintptr_t)15);
    int2* REC   = (int2*)wsb;             wsb += (size_t)Etot * 8;
    float* OUT  = (float*)d_out;

    const int nb2       = (M2 + 1023) / 1024;   // 98
    const int nb_scan   = (N + 1023) / 1024;    // 49
    const int gemm_grid = (N + 63) / 64;        // 782
    const int e2_grid   = (N + 15) / 16;

    // -------- W conversions (tiny) --------
    cvt_w_kernel<<<(96 * 128 + 255) / 256, 256, 0, stream>>>(W1, WTH1, WTL1, 128);
    cvt_w_kernel<<<(96 * 96 + 255) / 256, 256, 0, stream>>>(W2, WTH2, WTL2, 96);

    // -------- CSR build: counting sort, zero global atomics --------
    hist2d_kernel<<<NBLK, 1024, 0, stream>>>(dsti, HIST2D, E0, Etot, nbins);
    scan_block_kernel<<<nb2, 1024, 0, stream>>>(HIST2D, SC2D, BSUM, M2);
    scan_bsum_kernel<<<1, 64, 0, stream>>>(BSUM, nb2);
    scan_add_kernel<<<(M2 + 255) / 256, 256, 0, stream>>>(SC2D, BSUM, M2, Etot);
    place_kernel<<<NBLK, 1024, 0, stream>>>(srci, dsti, SC2D, REC, E0, Etot);
    bucketDeg_kernel<<<nbins, 256, 0, stream>>>(SC2D, REC, DEG, N);
    scan_block_kernel<<<nb_scan, 1024, 0, stream>>>(DEG, ROWPTR, BSUM, N);
    scan_bsum_kernel<<<1, 64, 0, stream>>>(BSUM, nb_scan);
    scan_add_kernel<<<(N + 255) / 256, 256, 0, stream>>>(ROWPTR, BSUM, N, Etot);
    bucketC_kernel<<<nbins, 256, 0, stream>>>(SC2D, REC, ROWPTR, COL);

    // -------- layer 1 --------
    gemm_mfma_att<128><<<gemm_grid, 256, 0, stream>>>(x, WTH1, WTL1, as1, ad1, H, AS, AD, N);
    edge2_vec_kernel<<<e2_grid, 384, 0, stream>>>(ROWPTR, COL, H, AS, AD, b1, H1, N);

    // -------- layer 2 --------
    gemm_mfma_att<96><<<gemm_grid, 256, 0, stream>>>(H1, WTH2, WTL2, as2, ad2, H, AS, AD, N);
    edge2_vec_kernel<<<e2_grid, 384, 0, stream>>>(ROWPTR, COL, H, AS, AD, b2, OUT, N);
}

// Round 9
// 355.480 us; speedup vs baseline: 1.0711x; 1.0711x over previous
//
#include <hip/hip_runtime.h>
#include <hip/hip_bf16.h>

#define NHEAD 8
#define CDIM 12
#define DMODEL 96
#define NBLK 128        // blocks in the counting-sort pass

typedef __attribute__((ext_vector_type(8))) short bf16x8;
typedef __attribute__((ext_vector_type(8))) unsigned short u16x8;
typedef __attribute__((ext_vector_type(4))) float f32x4;

__device__ __forceinline__ unsigned short f2bf(float f) {
    unsigned int u = __float_as_uint(f);
    unsigned int r = (u + 0x7fffu + ((u >> 16) & 1u)) >> 16;   // RNE
    return (unsigned short)r;
}

// ---------------- W -> transposed split-bf16 (tiny, once) ----------------
__global__ void cvt_w_kernel(const float* __restrict__ W,   // [K][96]
                             unsigned short* __restrict__ Wth,
                             unsigned short* __restrict__ Wtl, int K)
{
    int idx = blockIdx.x * 256 + threadIdx.x;   // flat c*K + k
    if (idx >= 96 * K) return;
    int c = idx / K, k = idx - c * K;
    float f = W[k * 96 + c];
    unsigned short h = f2bf(f);
    float hf = __uint_as_float((unsigned int)h << 16);
    Wth[idx] = h;
    Wtl[idx] = f2bf(f - hf);
}

// ---------------- MFMA GEMM + fused attention coefficients (v2) -----------
// H[N,96] = X @ W via split-bf16 (xh*wh + xl*wh + xh*wl).
// 256 thr = 4 waves; wave w: rows n0+16w..+15 x 96 cols (6 16x16x32 tiles).
// B planes (Wth/Wtl, [96][K]) staged to LDS once, XOR-swizzled chunks,
// read as conflict-free ds_read_b128. Full X row prefetched to registers
// before the k-loop -> k-loop is pure {2 ds_read + 3 MFMA} x 6 tiles.
template<int K>
__global__ __launch_bounds__(256) void gemm_mfma_att(
    const float* __restrict__ X,
    const unsigned short* __restrict__ Wth,
    const unsigned short* __restrict__ Wtl,
    const float* __restrict__ att_s, const float* __restrict__ att_d,
    float* __restrict__ H, float* __restrict__ a_s, float* __restrict__ a_d,
    int N)
{
    constexpr int NKC = K / 32;        // k-chunks of 32
    constexpr int NCH = K / 8;         // 16B chunks per col (12 or 16)
    __shared__ unsigned short wlsH[96 * 128];   // padded stripe: 16 chunks/col
    __shared__ unsigned short wlsL[96 * 128];
    __shared__ float redS[64][8];
    __shared__ float redD[64][8];
    const int t = threadIdx.x;
    const int w = t >> 6;
    const int lane = t & 63;
    const int l16 = lane & 15, lhi = lane >> 4;
    const int n0 = blockIdx.x * 64;
    const int growA = n0 + 16 * w + l16;
    const int growC = (growA < N) ? growA : (N - 1);

    for (int e = t; e < 512; e += 256) {
        ((float*)redS)[e] = 0.f;
        ((float*)redD)[e] = 0.f;
    }

    // ---- stage B planes into LDS (swizzled 16B chunks) ----
    for (int q = t; q < 96 * NCH; q += 256) {
        const int col = q / NCH, ck = q - col * NCH;
        const int dst = col * 128 + ((ck ^ (col & 7)) << 3);
        *(u16x8*)&wlsH[dst] = *(const u16x8*)(Wth + (size_t)q * 8);
        *(u16x8*)&wlsL[dst] = *(const u16x8*)(Wtl + (size_t)q * 8);
    }

    // ---- prefetch entire X row into registers, convert to split-bf16 ----
    const float* xrow = X + (size_t)growC * K;
    float4 xa[NKC], xb[NKC];
#pragma unroll
    for (int kc = 0; kc < NKC; ++kc) {
        xa[kc] = *(const float4*)(xrow + kc * 32 + lhi * 8);
        xb[kc] = *(const float4*)(xrow + kc * 32 + lhi * 8 + 4);
    }
    bf16x8 ah[NKC], al[NKC];
#pragma unroll
    for (int kc = 0; kc < NKC; ++kc) {
        float xv[8] = {xa[kc].x, xa[kc].y, xa[kc].z, xa[kc].w,
                       xb[kc].x, xb[kc].y, xb[kc].z, xb[kc].w};
#pragma unroll
        for (int j = 0; j < 8; ++j) {
            unsigned short h = f2bf(xv[j]);
            float hf = __uint_as_float((unsigned int)h << 16);
            ah[kc][j] = (short)h;
            al[kc][j] = (short)f2bf(xv[j] - hf);
        }
    }

    f32x4 acc[6];
#pragma unroll
    for (int ct = 0; ct < 6; ++ct) acc[ct] = (f32x4){0.f, 0.f, 0.f, 0.f};

    __syncthreads();   // B planes staged

    // ---- k-loop: pure LDS reads + MFMA, no barriers ----
#pragma unroll
    for (int kc = 0; kc < NKC; ++kc) {
        const int ck = kc * 4 + lhi;             // this lane's chunk index
#pragma unroll
        for (int ct = 0; ct < 6; ++ct) {
            const int col = ct * 16 + l16;
            const int off = col * 128 + ((ck ^ (col & 7)) << 3);
            bf16x8 bh = *(const bf16x8*)&wlsH[off];
            bf16x8 bl = *(const bf16x8*)&wlsL[off];
            acc[ct] = __builtin_amdgcn_mfma_f32_16x16x32_bf16(ah[kc], bh, acc[ct], 0, 0, 0);
            acc[ct] = __builtin_amdgcn_mfma_f32_16x16x32_bf16(al[kc], bh, acc[ct], 0, 0, 0);
            acc[ct] = __builtin_amdgcn_mfma_f32_16x16x32_bf16(ah[kc], bl, acc[ct], 0, 0, 0);
        }
    }

    // ---- epilogue: store H + fused att partials (LDS atomics) ----
    const int orowL = 16 * w + lhi * 4;
#pragma unroll
    for (int ct = 0; ct < 6; ++ct) {
        const int c = ct * 16 + l16;
        const float as_c = att_s[c];
        const float ad_c = att_d[c];
        const int hh = c / CDIM;
#pragma unroll
        for (int j = 0; j < 4; ++j) {
            float v = acc[ct][j];
            int rL = orowL + j;
            int gr = n0 + rL;
            if (gr < N) H[(size_t)gr * 96 + c] = v;
            atomicAdd(&redS[rL][hh], v * as_c);
            atomicAdd(&redD[rL][hh], v * ad_c);
        }
    }
    __syncthreads();
    for (int e = t; e < 512; e += 256) {
        int rL = e >> 3, hh = e & 7;
        int gr = n0 + rL;
        if (gr < N) {
            a_s[gr * NHEAD + hh] = redS[rL][hh];
            a_d[gr * NHEAD + hh] = redD[rL][hh];
        }
    }
}

// ---------------- CSR build: two-level counting sort, no global atomics ----
__global__ __launch_bounds__(1024) void hist2d_kernel(
    const int* __restrict__ dsti, int* __restrict__ hist2d,
    int E0, int Etot, int nbins)
{
    __shared__ int hist[1024];
    const int t = threadIdx.x, b = blockIdx.x;
    hist[t] = 0;
    __syncthreads();
    const int chunk = (Etot + NBLK - 1) / NBLK;
    const int e0 = b * chunk;
    const int e1 = (e0 + chunk < Etot) ? e0 + chunk : Etot;
    for (int e = e0 + t; e < e1; e += 1024) {
        int d = (e < E0) ? dsti[e] : e - E0;
        atomicAdd(&hist[d >> 6], 1);
    }
    __syncthreads();
    if (t < nbins) hist2d[(size_t)t * NBLK + b] = hist[t];
}

__global__ __launch_bounds__(1024) void place_kernel(
    const int* __restrict__ srci, const int* __restrict__ dsti,
    const int* __restrict__ sc2d, int2* __restrict__ rec,
    int E0, int Etot)
{
    __shared__ int run[1024];
    const int t = threadIdx.x, b = blockIdx.x;
    run[t] = 0;
    __syncthreads();
    const int chunk = (Etot + NBLK - 1) / NBLK;
    const int e0 = b * chunk;
    const int e1 = (e0 + chunk < Etot) ? e0 + chunk : Etot;
    for (int e = e0 + t; e < e1; e += 1024) {
        int s, d;
        if (e < E0) { s = srci[e]; d = dsti[e]; }
        else        { s = d = e - E0; }
        int bin = d >> 6;
        int r = atomicAdd(&run[bin], 1);
        rec[(size_t)sc2d[bin * NBLK + b] + r] = make_int2(d, s);
    }
}

__global__ __launch_bounds__(256) void bucketDeg_kernel(
    const int* __restrict__ sc2d, const int2* __restrict__ rec,
    int* __restrict__ deg, int N)
{
    __shared__ int deg64[64];
    const int t = threadIdx.x, b = blockIdx.x;
    if (t < 64) deg64[t] = 0;
    __syncthreads();
    const int r0 = sc2d[b * NBLK], r1 = sc2d[(b + 1) * NBLK];
    for (int i = r0 + t; i < r1; i += 256)
        atomicAdd(&deg64[rec[i].x & 63], 1);
    __syncthreads();
    const int gn = b * 64 + t;
    if (t < 64 && gn < N) deg[gn] = deg64[t];
}

__global__ __launch_bounds__(256) void bucketC_kernel(
    const int* __restrict__ sc2d, const int2* __restrict__ rec,
    const int* __restrict__ rowptr, int* __restrict__ col)
{
    __shared__ int run64[64];
    const int t = threadIdx.x, b = blockIdx.x;
    if (t < 64) run64[t] = 0;
    __syncthreads();
    const int r0 = sc2d[b * NBLK], r1 = sc2d[(b + 1) * NBLK];
    for (int i = r0 + t; i < r1; i += 256) {
        int2 v = rec[i];
        int rank = atomicAdd(&run64[v.x & 63], 1);
        col[rowptr[v.x] + rank] = v.y;
    }
}

// ---------------- generic scan chain (exclusive) ----------------
__global__ __launch_bounds__(1024) void scan_block_kernel(
    const int* __restrict__ in, int* __restrict__ out,
    int* __restrict__ bsum, int n)
{
    __shared__ int sh[1024];
    int t = threadIdx.x, g = blockIdx.x * 1024 + t;
    int v = (g < n) ? in[g] : 0;
    sh[t] = v;
    __syncthreads();
    for (int off = 1; off < 1024; off <<= 1) {
        int add = (t >= off) ? sh[t - off] : 0;
        __syncthreads();
        sh[t] += add;
        __syncthreads();
    }
    if (g < n) out[g] = sh[t] - v;     // exclusive
    if (t == 1023) bsum[blockIdx.x] = sh[t];
}

__global__ void scan_bsum_kernel(int* bsum, int nb)
{
    if (threadIdx.x == 0) {
        int acc = 0;
        for (int i = 0; i < nb; ++i) { int v = bsum[i]; bsum[i] = acc; acc += v; }
    }
}

__global__ void scan_add_kernel(int* __restrict__ arr, const int* __restrict__ bsum,
                                int n, int total)
{
    int g = blockIdx.x * blockDim.x + threadIdx.x;
    if (g < n) arr[g] += bsum[g >> 10];
    if (g == 0) arr[n] = total;        // sentinel
}

// ---------------- edge pass (CSR): gather + fused softmax-denominator ------
__global__ __launch_bounds__(384) void edge2_vec_kernel(
    const int* __restrict__ rowptr, const int* __restrict__ col,
    const float* __restrict__ H, const float* __restrict__ a_s,
    const float* __restrict__ a_d, const float* __restrict__ bias,
    float* __restrict__ out, int N)
{
    const int grp  = threadIdx.x / 24;      // 16 nodes/block
    const int lane = threadIdx.x % 24;      // float4 chunk
    const int d = blockIdx.x * 16 + grp;
    if (d >= N) return;
    const int hh = lane / 3;
    const float ad  = a_d[d * NHEAD + hh];
    const float4* __restrict__ H4 = (const float4*)H;

    int j0 = rowptr[d], j1 = rowptr[d + 1];
    float4 acc = make_float4(0.f, 0.f, 0.f, 0.f);
    float den = 1e-16f;
    int j = j0;
    for (; j + 3 < j1; j += 4) {
        int s0 = col[j], s1 = col[j+1], s2 = col[j+2], s3 = col[j+3];
        float v0 = a_s[s0 * NHEAD + hh] + ad;
        float v1 = a_s[s1 * NHEAD + hh] + ad;
        float v2 = a_s[s2 * NHEAD + hh] + ad;
        float v3 = a_s[s3 * NHEAD + hh] + ad;
        float4 h0 = H4[(size_t)s0 * 24 + lane];
        float4 h1 = H4[(size_t)s1 * 24 + lane];
        float4 h2 = H4[(size_t)s2 * 24 + lane];
        float4 h3 = H4[(size_t)s3 * 24 + lane];
        v0 = v0 > 0.f ? v0 : 0.2f * v0;
        v1 = v1 > 0.f ? v1 : 0.2f * v1;
        v2 = v2 > 0.f ? v2 : 0.2f * v2;
        v3 = v3 > 0.f ? v3 : 0.2f * v3;
        float e0 = __expf(v0), e1 = __expf(v1), e2 = __expf(v2), e3 = __expf(v3);
        den += e0 + e1 + e2 + e3;
        acc.x = fmaf(e0, h0.x, acc.x); acc.y = fmaf(e0, h0.y, acc.y);
        acc.z = fmaf(e0, h0.z, acc.z); acc.w = fmaf(e0, h0.w, acc.w);
        acc.x = fmaf(e1, h1.x, acc.x); acc.y = fmaf(e1, h1.y, acc.y);
        acc.z = fmaf(e1, h1.z, acc.z); acc.w = fmaf(e1, h1.w, acc.w);
        acc.x = fmaf(e2, h2.x, acc.x); acc.y = fmaf(e2, h2.y, acc.y);
        acc.z = fmaf(e2, h2.z, acc.z); acc.w = fmaf(e2, h2.w, acc.w);
        acc.x = fmaf(e3, h3.x, acc.x); acc.y = fmaf(e3, h3.y, acc.y);
        acc.z = fmaf(e3, h3.z, acc.z); acc.w = fmaf(e3, h3.w, acc.w);
    }
    for (; j < j1; ++j) {
        int s = col[j];
        float v = a_s[s * NHEAD + hh] + ad;
        v = v > 0.f ? v : 0.2f * v;
        float ex = __expf(v);
        den += ex;
        float4 hv = H4[(size_t)s * 24 + lane];
        acc.x = fmaf(ex, hv.x, acc.x); acc.y = fmaf(ex, hv.y, acc.y);
        acc.z = fmaf(ex, hv.z, acc.z); acc.w = fmaf(ex, hv.w, acc.w);
    }
    float inv = 1.0f / den;
    float4 bv = ((const float4*)bias)[lane];
    float4 o;
    o.x = fmaf(acc.x, inv, bv.x); o.y = fmaf(acc.y, inv, bv.y);
    o.z = fmaf(acc.z, inv, bv.z); o.w = fmaf(acc.w, inv, bv.w);
    o.x = o.x > 0.f ? o.x : 0.f;  o.y = o.y > 0.f ? o.y : 0.f;
    o.z = o.z > 0.f ? o.z : 0.f;  o.w = o.w > 0.f ? o.w : 0.f;
    ((float4*)out)[(size_t)d * 24 + lane] = o;
}

extern "C" void kernel_launch(void* const* d_in, const int* in_sizes, int n_in,
                              void* d_out, int out_size, void* d_ws, size_t ws_size,
                              hipStream_t stream) {
    const float* x   = (const float*)d_in[0];
    const int*   ei  = (const int*)d_in[1];
    const float* W1  = (const float*)d_in[2];
    const float* as1 = (const float*)d_in[3];
    const float* ad1 = (const float*)d_in[4];
    const float* b1  = (const float*)d_in[5];
    const float* W2  = (const float*)d_in[6];
    const float* as2 = (const float*)d_in[7];
    const float* ad2 = (const float*)d_in[8];
    const float* b2  = (const float*)d_in[9];

    const int N    = in_sizes[0] / 128;   // 50000
    const int E0   = in_sizes[1] / 2;     // 800000
    const int Etot = E0 + N;
    const int* srci = ei;
    const int* dsti = ei + E0;
    const int nbins = (N + 63) >> 6;      // 782
    const int M2    = nbins * NBLK;       // 100096

    // -------- workspace layout --------
    char* wsb = (char*)d_ws;
    float* H    = (float*)wsb;            wsb += (size_t)N * DMODEL * 4;
    float* H1   = (float*)wsb;            wsb += (size_t)N * DMODEL * 4;
    float* AS   = (float*)wsb;            wsb += (size_t)N * NHEAD * 4;
    float* AD   = (float*)wsb;            wsb += (size_t)N * NHEAD * 4;
    int* HIST2D = (int*)wsb;              wsb += (size_t)M2 * 4;
    int* SC2D   = (int*)wsb;              wsb += (size_t)(M2 + 1) * 4;
    int* DEG    = (int*)wsb;              wsb += (size_t)N * 4;
    int* ROWPTR = (int*)wsb;              wsb += (size_t)(N + 1) * 4;
    int* BSUM   = (int*)wsb;              wsb += 256 * 4;
    int* COL    = (int*)wsb;              wsb += (size_t)Etot * 4;
    wsb = (char*)(((uintptr_t)wsb + 15) & ~(uintptr_t)15);
    unsigned short* WTH1 = (unsigned short*)wsb; wsb += 96 * 128 * 2;
    unsigned short* WTL1 = (unsigned short*)wsb; wsb += 96 * 128 * 2;
    unsigned short* WTH2 = (unsigned short*)wsb; wsb += 96 * 96 * 2;
    unsigned short* WTL2 = (unsigned short*)wsb; wsb += 96 * 96 * 2;
    wsb = (char*)(((uintptr_t)wsb + 15) & ~(uintptr_t)15);
    int2* REC   = (int2*)wsb;             wsb += (size_t)Etot * 8;
    float* OUT  = (float*)d_out;

    const int nb2       = (M2 + 1023) / 1024;   // 98
    const int nb_scan   = (N + 1023) / 1024;    // 49
    const int gemm_grid = (N + 63) / 64;        // 782
    const int e2_grid   = (N + 15) / 16;

    // -------- W conversions (tiny) --------
    cvt_w_kernel<<<(96 * 128 + 255) / 256, 256, 0, stream>>>(W1, WTH1, WTL1, 128);
    cvt_w_kernel<<<(96 * 96 + 255) / 256, 256, 0, stream>>>(W2, WTH2, WTL2, 96);

    // -------- CSR build: counting sort, zero global atomics --------
    hist2d_kernel<<<NBLK, 1024, 0, stream>>>(dsti, HIST2D, E0, Etot, nbins);
    scan_block_kernel<<<nb2, 1024, 0, stream>>>(HIST2D, SC2D, BSUM, M2);
    scan_bsum_kernel<<<1, 64, 0, stream>>>(BSUM, nb2);
    scan_add_kernel<<<(M2 + 255) / 256, 256, 0, stream>>>(SC2D, BSUM, M2, Etot);
    place_kernel<<<NBLK, 1024, 0, stream>>>(srci, dsti, SC2D, REC, E0, Etot);
    bucketDeg_kernel<<<nbins, 256, 0, stream>>>(SC2D, REC, DEG, N);
    scan_block_kernel<<<nb_scan, 1024, 0, stream>>>(DEG, ROWPTR, BSUM, N);
    scan_bsum_kernel<<<1, 64, 0, stream>>>(BSUM, nb_scan);
    scan_add_kernel<<<(N + 255) / 256, 256, 0, stream>>>(ROWPTR, BSUM, N, Etot);
    bucketC_kernel<<<nbins, 256, 0, stream>>>(SC2D, REC, ROWPTR, COL);

    // -------- layer 1 --------
    gemm_mfma_att<128><<<gemm_grid, 256, 0, stream>>>(x, WTH1, WTL1, as1, ad1, H, AS, AD, N);
    edge2_vec_kernel<<<e2_grid, 384, 0, stream>>>(ROWPTR, COL, H, AS, AD, b1, H1, N);

    // -------- layer 2 --------
    gemm_mfma_att<96><<<gemm_grid, 256, 0, stream>>>(H1, WTH2, WTL2, as2, ad2, H, AS, AD, N);
    edge2_vec_kernel<<<e2_grid, 384, 0, stream>>>(ROWPTR, COL, H, AS, AD, b2, OUT, N);
}

// Round 10
// 219.817 us; speedup vs baseline: 1.7321x; 1.6172x over previous
//
#include <hip/hip_runtime.h>
#include <hip/hip_bf16.h>

#define NHEAD 8
#define CDIM 12
#define DMODEL 96
#define NBLK 128        // blocks in the counting-sort pass

__device__ __forceinline__ unsigned short f2bf(float f) {
    unsigned int u = __float_as_uint(f);
    unsigned int r = (u + 0x7fffu + ((u >> 16) & 1u)) >> 16;   // RNE
    return (unsigned short)r;
}

__device__ __forceinline__ float4 bf4_to_f4(ushort4 v) {
    float4 r;
    r.x = __uint_as_float((unsigned int)v.x << 16);
    r.y = __uint_as_float((unsigned int)v.y << 16);
    r.z = __uint_as_float((unsigned int)v.z << 16);
    r.w = __uint_as_float((unsigned int)v.w << 16);
    return r;
}

// ---------------- fused GEMM + attention coefficients (R7 pipeline) --------
// H16[N,96](bf16) = X[N,K] @ W[K,96]; a_s/a_d fused (fp32 accurate).
// 192 threads = (c4=t/8, y=t%8), 32 nodes/block, 4x4 register tile/thread.
// X and W stream through 32-k-row LDS chunks with register double-buffering.
template<int K>
__global__ __launch_bounds__(192) void gemm_att_fused(
    const float* __restrict__ X, const float* __restrict__ W,
    const float* __restrict__ att_s, const float* __restrict__ att_d,
    unsigned short* __restrict__ H16, float* __restrict__ a_s,
    float* __restrict__ a_d, int N)
{
    constexpr int KQ = K / 4;          // float4 per X row
    constexpr int NC = K / 32;         // k-chunks
    __shared__ float xs[32][32];       // X^T chunk, XOR-swizzled cols
    __shared__ float wsh[32 * 96];     // W chunk (12 KB)
    __shared__ float red[32][16];      // [node][head*2 + (s|d)]
    const int t  = threadIdx.x;
    const int c4 = t / 8;              // 0..23
    const int y  = t % 8;              // 0..7
    const int n0 = blockIdx.x * 32;
    const float4 z4 = make_float4(0.f, 0.f, 0.f, 0.f);

    for (int e = t; e < 512; e += 192) ((float*)red)[e] = 0.f;

    const int xn0 = t >> 3,  xkq0 = t & 7;
    const int xn1 = (t + 192) >> 3, xkq1 = (t + 192) & 7;
    const int gn0 = n0 + xn0, gn1 = n0 + xn1;

    float4 px0, px1, pw[4];
    px0 = (gn0 < N) ? ((const float4*)X)[(size_t)gn0 * KQ + xkq0] : z4;
    if (t < 64) px1 = (gn1 < N) ? ((const float4*)X)[(size_t)gn1 * KQ + xkq1] : z4;
#pragma unroll
    for (int p = 0; p < 4; ++p) pw[p] = ((const float4*)W)[t + p * 192];

    float4 acc[4];
#pragma unroll
    for (int i = 0; i < 4; ++i) acc[i] = z4;

    for (int c = 0; c < NC; ++c) {
        __syncthreads();
        {
            const int col0 = xn0 ^ (xkq0 << 2);
            xs[4 * xkq0 + 0][col0] = px0.x;
            xs[4 * xkq0 + 1][col0] = px0.y;
            xs[4 * xkq0 + 2][col0] = px0.z;
            xs[4 * xkq0 + 3][col0] = px0.w;
            if (t < 64) {
                const int col1 = xn1 ^ (xkq1 << 2);
                xs[4 * xkq1 + 0][col1] = px1.x;
                xs[4 * xkq1 + 1][col1] = px1.y;
                xs[4 * xkq1 + 2][col1] = px1.z;
                xs[4 * xkq1 + 3][col1] = px1.w;
            }
#pragma unroll
            for (int p = 0; p < 4; ++p) ((float4*)wsh)[t + p * 192] = pw[p];
        }
        __syncthreads();
        if (c + 1 < NC) {
            const int k0q = (c + 1) * 8;
            px0 = (gn0 < N) ? ((const float4*)X)[(size_t)gn0 * KQ + k0q + xkq0] : z4;
            if (t < 64)
                px1 = (gn1 < N) ? ((const float4*)X)[(size_t)gn1 * KQ + k0q + xkq1] : z4;
#pragma unroll
            for (int p = 0; p < 4; ++p)
                pw[p] = ((const float4*)W)[(c + 1) * 768 + t + p * 192];
        }
#pragma unroll 4
        for (int kk = 0; kk < 32; ++kk) {
            const float4 wv = *(const float4*)&wsh[kk * 96 + c4 * 4];
            const int q = (kk >> 2) & 7;
            const float4 xv = *(const float4*)&xs[kk][4 * (y ^ q)];
            acc[0].x = fmaf(xv.x, wv.x, acc[0].x);
            acc[0].y = fmaf(xv.x, wv.y, acc[0].y);
            acc[0].z = fmaf(xv.x, wv.z, acc[0].z);
            acc[0].w = fmaf(xv.x, wv.w, acc[0].w);
            acc[1].x = fmaf(xv.y, wv.x, acc[1].x);
            acc[1].y = fmaf(xv.y, wv.y, acc[1].y);
            acc[1].z = fmaf(xv.y, wv.z, acc[1].z);
            acc[1].w = fmaf(xv.y, wv.w, acc[1].w);
            acc[2].x = fmaf(xv.z, wv.x, acc[2].x);
            acc[2].y = fmaf(xv.z, wv.y, acc[2].y);
            acc[2].z = fmaf(xv.z, wv.z, acc[2].z);
            acc[2].w = fmaf(xv.z, wv.w, acc[2].w);
            acc[3].x = fmaf(xv.w, wv.x, acc[3].x);
            acc[3].y = fmaf(xv.w, wv.y, acc[3].y);
            acc[3].z = fmaf(xv.w, wv.z, acc[3].z);
            acc[3].w = fmaf(xv.w, wv.w, acc[3].w);
        }
    }

    // ---- fused attention-coefficient partials (fp32) ----
    const int h = c4 / 3;
    const float4 asv = ((const float4*)att_s)[c4];
    const float4 adv = ((const float4*)att_d)[c4];
#pragma unroll
    for (int i = 0; i < 4; ++i) {
        const int m = 4 * y + i;
        float ps = acc[i].x * asv.x + acc[i].y * asv.y
                 + acc[i].z * asv.z + acc[i].w * asv.w;
        float pd = acc[i].x * adv.x + acc[i].y * adv.y
                 + acc[i].z * adv.z + acc[i].w * adv.w;
        atomicAdd(&red[m][h * 2 + 0], ps);
        atomicAdd(&red[m][h * 2 + 1], pd);
    }

    // ---- H store as bf16 (halves message-gather traffic downstream) ----
#pragma unroll
    for (int i = 0; i < 4; ++i) {
        const int gn = n0 + 4 * y + i;
        if (gn < N) {
            ushort4 hv;
            hv.x = f2bf(acc[i].x);
            hv.y = f2bf(acc[i].y);
            hv.z = f2bf(acc[i].z);
            hv.w = f2bf(acc[i].w);
            ((ushort4*)H16)[(size_t)gn * 24 + c4] = hv;
        }
    }

    __syncthreads();
    for (int e = t; e < 256; e += 192) {
        const int m = e >> 3, hh = e & 7;
        const int gn = n0 + m;
        if (gn < N) {
            a_s[gn * NHEAD + hh] = red[m][hh * 2 + 0];
            a_d[gn * NHEAD + hh] = red[m][hh * 2 + 1];
        }
    }
}

// ---------------- CSR build: two-level counting sort, no global atomics ----
__global__ __launch_bounds__(1024) void hist2d_kernel(
    const int* __restrict__ dsti, int* __restrict__ hist2d,
    int E0, int Etot, int nbins)
{
    __shared__ int hist[1024];
    const int t = threadIdx.x, b = blockIdx.x;
    hist[t] = 0;
    __syncthreads();
    const int chunk = (Etot + NBLK - 1) / NBLK;
    const int e0 = b * chunk;
    const int e1 = (e0 + chunk < Etot) ? e0 + chunk : Etot;
    for (int e = e0 + t; e < e1; e += 1024) {
        int d = (e < E0) ? dsti[e] : e - E0;
        atomicAdd(&hist[d >> 6], 1);
    }
    __syncthreads();
    if (t < nbins) hist2d[(size_t)t * NBLK + b] = hist[t];
}

// records packed: (d<<16)|s  (both < 65536)
__global__ __launch_bounds__(1024) void place_kernel(
    const int* __restrict__ srci, const int* __restrict__ dsti,
    const int* __restrict__ sc2d, unsigned int* __restrict__ rec,
    int E0, int Etot)
{
    __shared__ int run[1024];
    const int t = threadIdx.x, b = blockIdx.x;
    run[t] = 0;
    __syncthreads();
    const int chunk = (Etot + NBLK - 1) / NBLK;
    const int e0 = b * chunk;
    const int e1 = (e0 + chunk < Etot) ? e0 + chunk : Etot;
    for (int e = e0 + t; e < e1; e += 1024) {
        int s, d;
        if (e < E0) { s = srci[e]; d = dsti[e]; }
        else        { s = d = e - E0; }
        int bin = d >> 6;
        int r = atomicAdd(&run[bin], 1);
        rec[(size_t)sc2d[bin * NBLK + b] + r] =
            ((unsigned int)d << 16) | (unsigned int)s;
    }
}

__global__ __launch_bounds__(256) void bucketDeg_kernel(
    const int* __restrict__ sc2d, const unsigned int* __restrict__ rec,
    int* __restrict__ deg, int N)
{
    __shared__ int deg64[64];
    const int t = threadIdx.x, b = blockIdx.x;
    if (t < 64) deg64[t] = 0;
    __syncthreads();
    const int r0 = sc2d[b * NBLK], r1 = sc2d[(b + 1) * NBLK];
    for (int i = r0 + t; i < r1; i += 256)
        atomicAdd(&deg64[(rec[i] >> 16) & 63], 1);
    __syncthreads();
    const int gn = b * 64 + t;
    if (t < 64 && gn < N) deg[gn] = deg64[t];
}

__global__ __launch_bounds__(256) void bucketC_kernel(
    const int* __restrict__ sc2d, const unsigned int* __restrict__ rec,
    const int* __restrict__ rowptr, int* __restrict__ col)
{
    __shared__ int run64[64];
    const int t = threadIdx.x, b = blockIdx.x;
    if (t < 64) run64[t] = 0;
    __syncthreads();
    const int r0 = sc2d[b * NBLK], r1 = sc2d[(b + 1) * NBLK];
    for (int i = r0 + t; i < r1; i += 256) {
        unsigned int v = rec[i];
        int d = (int)(v >> 16);
        int s = (int)(v & 0xFFFFu);
        int rank = atomicAdd(&run64[d & 63], 1);
        col[rowptr[d] + rank] = s;
    }
}

// ---------------- generic scan chain (exclusive) ----------------
__global__ __launch_bounds__(1024) void scan_block_kernel(
    const int* __restrict__ in, int* __restrict__ out,
    int* __restrict__ bsum, int n)
{
    __shared__ int sh[1024];
    int t = threadIdx.x, g = blockIdx.x * 1024 + t;
    int v = (g < n) ? in[g] : 0;
    sh[t] = v;
    __syncthreads();
    for (int off = 1; off < 1024; off <<= 1) {
        int add = (t >= off) ? sh[t - off] : 0;
        __syncthreads();
        sh[t] += add;
        __syncthreads();
    }
    if (g < n) out[g] = sh[t] - v;     // exclusive
    if (t == 1023) bsum[blockIdx.x] = sh[t];
}

__global__ void scan_bsum_kernel(int* bsum, int nb)
{
    if (threadIdx.x == 0) {
        int acc = 0;
        for (int i = 0; i < nb; ++i) { int v = bsum[i]; bsum[i] = acc; acc += v; }
    }
}

__global__ void scan_add_kernel(int* __restrict__ arr, const int* __restrict__ bsum,
                                int n, int total)
{
    int g = blockIdx.x * blockDim.x + threadIdx.x;
    if (g < n) arr[g] += bsum[g >> 10];
    if (g == 0) arr[n] = total;        // sentinel
}

// ---------------- edge pass (CSR): bf16 gather + fused softmax denom -------
__global__ __launch_bounds__(384) void edge2_vec_kernel(
    const int* __restrict__ rowptr, const int* __restrict__ col,
    const unsigned short* __restrict__ H16, const float* __restrict__ a_s,
    const float* __restrict__ a_d, const float* __restrict__ bias,
    float* __restrict__ out, int N)
{
    const int grp  = threadIdx.x / 24;      // 16 nodes/block
    const int lane = threadIdx.x % 24;      // 4-channel chunk
    const int d = blockIdx.x * 16 + grp;
    if (d >= N) return;
    const int hh = lane / 3;
    const float ad  = a_d[d * NHEAD + hh];
    const ushort4* __restrict__ Hc = (const ushort4*)H16;

    int j0 = rowptr[d], j1 = rowptr[d + 1];
    float4 acc = make_float4(0.f, 0.f, 0.f, 0.f);
    float den = 1e-16f;
    int j = j0;
    for (; j + 3 < j1; j += 4) {
        int s0 = col[j], s1 = col[j+1], s2 = col[j+2], s3 = col[j+3];
        float v0 = a_s[s0 * NHEAD + hh] + ad;
        float v1 = a_s[s1 * NHEAD + hh] + ad;
        float v2 = a_s[s2 * NHEAD + hh] + ad;
        float v3 = a_s[s3 * NHEAD + hh] + ad;
        ushort4 u0 = Hc[(size_t)s0 * 24 + lane];
        ushort4 u1 = Hc[(size_t)s1 * 24 + lane];
        ushort4 u2 = Hc[(size_t)s2 * 24 + lane];
        ushort4 u3 = Hc[(size_t)s3 * 24 + lane];
        v0 = v0 > 0.f ? v0 : 0.2f * v0;
        v1 = v1 > 0.f ? v1 : 0.2f * v1;
        v2 = v2 > 0.f ? v2 : 0.2f * v2;
        v3 = v3 > 0.f ? v3 : 0.2f * v3;
        float e0 = __expf(v0), e1 = __expf(v1), e2 = __expf(v2), e3 = __expf(v3);
        den += e0 + e1 + e2 + e3;
        float4 h0 = bf4_to_f4(u0), h1 = bf4_to_f4(u1);
        float4 h2 = bf4_to_f4(u2), h3 = bf4_to_f4(u3);
        acc.x = fmaf(e0, h0.x, acc.x); acc.y = fmaf(e0, h0.y, acc.y);
        acc.z = fmaf(e0, h0.z, acc.z); acc.w = fmaf(e0, h0.w, acc.w);
        acc.x = fmaf(e1, h1.x, acc.x); acc.y = fmaf(e1, h1.y, acc.y);
        acc.z = fmaf(e1, h1.z, acc.z); acc.w = fmaf(e1, h1.w, acc.w);
        acc.x = fmaf(e2, h2.x, acc.x); acc.y = fmaf(e2, h2.y, acc.y);
        acc.z = fmaf(e2, h2.z, acc.z); acc.w = fmaf(e2, h2.w, acc.w);
        acc.x = fmaf(e3, h3.x, acc.x); acc.y = fmaf(e3, h3.y, acc.y);
        acc.z = fmaf(e3, h3.z, acc.z); acc.w = fmaf(e3, h3.w, acc.w);
    }
    for (; j < j1; ++j) {
        int s = col[j];
        float v = a_s[s * NHEAD + hh] + ad;
        v = v > 0.f ? v : 0.2f * v;
        float ex = __expf(v);
        den += ex;
        float4 hv = bf4_to_f4(Hc[(size_t)s * 24 + lane]);
        acc.x = fmaf(ex, hv.x, acc.x); acc.y = fmaf(ex, hv.y, acc.y);
        acc.z = fmaf(ex, hv.z, acc.z); acc.w = fmaf(ex, hv.w, acc.w);
    }
    float inv = 1.0f / den;
    float4 bv = ((const float4*)bias)[lane];
    float4 o;
    o.x = fmaf(acc.x, inv, bv.x); o.y = fmaf(acc.y, inv, bv.y);
    o.z = fmaf(acc.z, inv, bv.z); o.w = fmaf(acc.w, inv, bv.w);
    o.x = o.x > 0.f ? o.x : 0.f;  o.y = o.y > 0.f ? o.y : 0.f;
    o.z = o.z > 0.f ? o.z : 0.f;  o.w = o.w > 0.f ? o.w : 0.f;
    ((float4*)out)[(size_t)d * 24 + lane] = o;
}

extern "C" void kernel_launch(void* const* d_in, const int* in_sizes, int n_in,
                              void* d_out, int out_size, void* d_ws, size_t ws_size,
                              hipStream_t stream) {
    const float* x   = (const float*)d_in[0];
    const int*   ei  = (const int*)d_in[1];
    const float* W1  = (const float*)d_in[2];
    const float* as1 = (const float*)d_in[3];
    const float* ad1 = (const float*)d_in[4];
    const float* b1  = (const float*)d_in[5];
    const float* W2  = (const float*)d_in[6];
    const float* as2 = (const float*)d_in[7];
    const float* ad2 = (const float*)d_in[8];
    const float* b2  = (const float*)d_in[9];

    const int N    = in_sizes[0] / 128;   // 50000
    const int E0   = in_sizes[1] / 2;     // 800000
    const int Etot = E0 + N;
    const int* srci = ei;
    const int* dsti = ei + E0;
    const int nbins = (N + 63) >> 6;      // 782
    const int M2    = nbins * NBLK;       // 100096

    // -------- workspace layout --------
    char* wsb = (char*)d_ws;
    unsigned short* H16 = (unsigned short*)wsb;  wsb += (size_t)N * DMODEL * 2;
    float* H1   = (float*)wsb;            wsb += (size_t)N * DMODEL * 4;
    float* AS   = (float*)wsb;            wsb += (size_t)N * NHEAD * 4;
    float* AD   = (float*)wsb;            wsb += (size_t)N * NHEAD * 4;
    int* HIST2D = (int*)wsb;              wsb += (size_t)M2 * 4;
    int* SC2D   = (int*)wsb;              wsb += (size_t)(M2 + 1) * 4;
    int* DEG    = (int*)wsb;              wsb += (size_t)N * 4;
    int* ROWPTR = (int*)wsb;              wsb += (size_t)(N + 1) * 4;
    int* BSUM   = (int*)wsb;              wsb += 256 * 4;
    int* COL    = (int*)wsb;              wsb += (size_t)Etot * 4;
    unsigned int* REC = (unsigned int*)wsb; wsb += (size_t)Etot * 4;
    float* OUT  = (float*)d_out;

    const int nb2       = (M2 + 1023) / 1024;   // 98
    const int nb_scan   = (N + 1023) / 1024;    // 49
    const int gemm_grid = (N + 31) / 32;
    const int e2_grid   = (N + 15) / 16;

    // -------- CSR build: counting sort, zero global atomics --------
    hist2d_kernel<<<NBLK, 1024, 0, stream>>>(dsti, HIST2D, E0, Etot, nbins);
    scan_block_kernel<<<nb2, 1024, 0, stream>>>(HIST2D, SC2D, BSUM, M2);
    scan_bsum_kernel<<<1, 64, 0, stream>>>(BSUM, nb2);
    scan_add_kernel<<<(M2 + 255) / 256, 256, 0, stream>>>(SC2D, BSUM, M2, Etot);
    place_kernel<<<NBLK, 1024, 0, stream>>>(srci, dsti, SC2D, REC, E0, Etot);
    bucketDeg_kernel<<<nbins, 256, 0, stream>>>(SC2D, REC, DEG, N);
    scan_block_kernel<<<nb_scan, 1024, 0, stream>>>(DEG, ROWPTR, BSUM, N);
    scan_bsum_kernel<<<1, 64, 0, stream>>>(BSUM, nb_scan);
    scan_add_kernel<<<(N + 255) / 256, 256, 0, stream>>>(ROWPTR, BSUM, N, Etot);
    bucketC_kernel<<<nbins, 256, 0, stream>>>(SC2D, REC, ROWPTR, COL);

    // -------- layer 1 --------
    gemm_att_fused<128><<<gemm_grid, 192, 0, stream>>>(x, W1, as1, ad1, H16, AS, AD, N);
    edge2_vec_kernel<<<e2_grid, 384, 0, stream>>>(ROWPTR, COL, H16, AS, AD, b1, H1, N);

    // -------- layer 2 --------
    gemm_att_fused<96><<<gemm_grid, 192, 0, stream>>>(H1, W2, as2, ad2, H16, AS, AD, N);
    edge2_vec_kernel<<<e2_grid, 384, 0, stream>>>(ROWPTR, COL, H16, AS, AD, b2, OUT, N);
}

// Round 11
// 183.741 us; speedup vs baseline: 2.0721x; 1.1963x over previous
//
#include <hip/hip_runtime.h>
#include <hip/hip_bf16.h>

#define NHEAD 8
#define CDIM 12
#define DMODEL 96
#define NBLK 128        // blocks in the counting-sort pass

__device__ __forceinline__ unsigned short f2bf(float f) {
    unsigned int u = __float_as_uint(f);
    unsigned int r = (u + 0x7fffu + ((u >> 16) & 1u)) >> 16;   // RNE
    return (unsigned short)r;
}

__device__ __forceinline__ float4 bf4_to_f4(ushort4 v) {
    float4 r;
    r.x = __uint_as_float((unsigned int)v.x << 16);
    r.y = __uint_as_float((unsigned int)v.y << 16);
    r.z = __uint_as_float((unsigned int)v.z << 16);
    r.w = __uint_as_float((unsigned int)v.w << 16);
    return r;
}

// ---------------- GEMM + fused att coeffs (v4: lane=node, scalar W) --------
// H16[N,96](bf16) = X[N,K] @ W[K,96]. 256 thr = 4 waves per 64 nodes.
// Wave w owns cols [24w,24w+24) = heads {2w,2w+1}. lane = node.
// W[k][c] is wave-uniform -> scalar s_load path; X per-lane global float4
// with rotate prefetch. No LDS, no barriers, no atomics; a_s/a_d per-lane.
template<int K>
__global__ __launch_bounds__(256) void gemm_scalar_att(
    const float* __restrict__ X, const float* __restrict__ W,
    const float* __restrict__ att_s, const float* __restrict__ att_d,
    unsigned short* __restrict__ H16, float* __restrict__ a_s,
    float* __restrict__ a_d, int N)
{
    const int t = threadIdx.x;
    const int w = __builtin_amdgcn_readfirstlane(t >> 6);   // wave id 0..3
    const int lane = t & 63;
    const int node = blockIdx.x * 64 + lane;
    const int nc = (node < N) ? node : (N - 1);
    const int c0 = __builtin_amdgcn_readfirstlane(w * 24);
    const float* __restrict__ xrow = X + (size_t)nc * K;

    float acc[24];
#pragma unroll
    for (int c = 0; c < 24; ++c) acc[c] = 0.f;

    float4 xv = *(const float4*)(xrow);
    for (int k4 = 0; k4 < K / 4; ++k4) {
        float4 nxt = make_float4(0.f, 0.f, 0.f, 0.f);
        if (k4 + 1 < K / 4) nxt = *(const float4*)(xrow + 4 * (k4 + 1));
        const float xk[4] = {xv.x, xv.y, xv.z, xv.w};
#pragma unroll
        for (int kk = 0; kk < 4; ++kk) {
            const float* __restrict__ wrow = W + (size_t)(k4 * 4 + kk) * 96 + c0;
#pragma unroll
            for (int c = 0; c < 24; ++c)
                acc[c] = fmaf(xk[kk], wrow[c], acc[c]);
        }
        xv = nxt;
    }

    if (node < N) {
        // H store (bf16)
#pragma unroll
        for (int q = 0; q < 6; ++q) {
            ushort4 hv;
            hv.x = f2bf(acc[4 * q + 0]);
            hv.y = f2bf(acc[4 * q + 1]);
            hv.z = f2bf(acc[4 * q + 2]);
            hv.w = f2bf(acc[4 * q + 3]);
            *(ushort4*)(H16 + (size_t)node * 96 + c0 + 4 * q) = hv;
        }
        // per-lane attention coefficients (2 whole heads per wave)
        const int h0 = 2 * w;
        float s0 = 0.f, s1 = 0.f, d0 = 0.f, d1 = 0.f;
#pragma unroll
        for (int i = 0; i < 12; ++i) {
            s0 = fmaf(acc[i],      att_s[h0 * 12 + i],       s0);
            d0 = fmaf(acc[i],      att_d[h0 * 12 + i],       d0);
            s1 = fmaf(acc[12 + i], att_s[(h0 + 1) * 12 + i], s1);
            d1 = fmaf(acc[12 + i], att_d[(h0 + 1) * 12 + i], d1);
        }
        a_s[node * NHEAD + h0]     = s0;
        a_s[node * NHEAD + h0 + 1] = s1;
        a_d[node * NHEAD + h0]     = d0;
        a_d[node * NHEAD + h0 + 1] = d1;
    }
}

// ---------------- CSR build: two-level counting sort, no global atomics ----
__global__ __launch_bounds__(1024) void hist2d_kernel(
    const int* __restrict__ dsti, int* __restrict__ hist2d,
    int E0, int Etot, int nbins)
{
    __shared__ int hist[1024];
    const int t = threadIdx.x, b = blockIdx.x;
    hist[t] = 0;
    __syncthreads();
    const int chunk = (Etot + NBLK - 1) / NBLK;
    const int e0 = b * chunk;
    const int e1 = (e0 + chunk < Etot) ? e0 + chunk : Etot;
    for (int e = e0 + t; e < e1; e += 1024) {
        int d = (e < E0) ? dsti[e] : e - E0;
        atomicAdd(&hist[d >> 6], 1);
    }
    __syncthreads();
    if (t < nbins) hist2d[(size_t)t * NBLK + b] = hist[t];
}

// records packed: (d<<16)|s  (both < 65536)
__global__ __launch_bounds__(1024) void place_kernel(
    const int* __restrict__ srci, const int* __restrict__ dsti,
    const int* __restrict__ sc2d, unsigned int* __restrict__ rec,
    int E0, int Etot)
{
    __shared__ int run[1024];
    const int t = threadIdx.x, b = blockIdx.x;
    run[t] = 0;
    __syncthreads();
    const int chunk = (Etot + NBLK - 1) / NBLK;
    const int e0 = b * chunk;
    const int e1 = (e0 + chunk < Etot) ? e0 + chunk : Etot;
    for (int e = e0 + t; e < e1; e += 1024) {
        int s, d;
        if (e < E0) { s = srci[e]; d = dsti[e]; }
        else        { s = d = e - E0; }
        int bin = d >> 6;
        int r = atomicAdd(&run[bin], 1);
        rec[(size_t)sc2d[bin * NBLK + b] + r] =
            ((unsigned int)d << 16) | (unsigned int)s;
    }
}

__global__ __launch_bounds__(256) void bucketDeg_kernel(
    const int* __restrict__ sc2d, const unsigned int* __restrict__ rec,
    int* __restrict__ deg, int N)
{
    __shared__ int deg64[64];
    const int t = threadIdx.x, b = blockIdx.x;
    if (t < 64) deg64[t] = 0;
    __syncthreads();
    const int r0 = sc2d[b * NBLK], r1 = sc2d[(b + 1) * NBLK];
    for (int i = r0 + t; i < r1; i += 256)
        atomicAdd(&deg64[(rec[i] >> 16) & 63], 1);
    __syncthreads();
    const int gn = b * 64 + t;
    if (t < 64 && gn < N) deg[gn] = deg64[t];
}

__global__ __launch_bounds__(256) void bucketC_kernel(
    const int* __restrict__ sc2d, const unsigned int* __restrict__ rec,
    const int* __restrict__ rowptr, int* __restrict__ col)
{
    __shared__ int run64[64];
    const int t = threadIdx.x, b = blockIdx.x;
    if (t < 64) run64[t] = 0;
    __syncthreads();
    const int r0 = sc2d[b * NBLK], r1 = sc2d[(b + 1) * NBLK];
    for (int i = r0 + t; i < r1; i += 256) {
        unsigned int v = rec[i];
        int d = (int)(v >> 16);
        int s = (int)(v & 0xFFFFu);
        int rank = atomicAdd(&run64[d & 63], 1);
        col[rowptr[d] + rank] = s;
    }
}

// ---------------- generic scan chain (exclusive) ----------------
__global__ __launch_bounds__(1024) void scan_block_kernel(
    const int* __restrict__ in, int* __restrict__ out,
    int* __restrict__ bsum, int n)
{
    __shared__ int sh[1024];
    int t = threadIdx.x, g = blockIdx.x * 1024 + t;
    int v = (g < n) ? in[g] : 0;
    sh[t] = v;
    __syncthreads();
    for (int off = 1; off < 1024; off <<= 1) {
        int add = (t >= off) ? sh[t - off] : 0;
        __syncthreads();
        sh[t] += add;
        __syncthreads();
    }
    if (g < n) out[g] = sh[t] - v;     // exclusive
    if (t == 1023) bsum[blockIdx.x] = sh[t];
}

__global__ void scan_bsum_kernel(int* bsum, int nb)
{
    if (threadIdx.x == 0) {
        int acc = 0;
        for (int i = 0; i < nb; ++i) { int v = bsum[i]; bsum[i] = acc; acc += v; }
    }
}

__global__ void scan_add_kernel(int* __restrict__ arr, const int* __restrict__ bsum,
                                int n, int total)
{
    int g = blockIdx.x * blockDim.x + threadIdx.x;
    if (g < n) arr[g] += bsum[g >> 10];
    if (g == 0) arr[n] = total;        // sentinel
}

// ---------------- edge pass (CSR): bf16 gather + fused softmax denom -------
__global__ __launch_bounds__(384) void edge2_vec_kernel(
    const int* __restrict__ rowptr, const int* __restrict__ col,
    const unsigned short* __restrict__ H16, const float* __restrict__ a_s,
    const float* __restrict__ a_d, const float* __restrict__ bias,
    float* __restrict__ out, int N)
{
    const int grp  = threadIdx.x / 24;      // 16 nodes/block
    const int lane = threadIdx.x % 24;      // 4-channel chunk
    const int d = blockIdx.x * 16 + grp;
    if (d >= N) return;
    const int hh = lane / 3;
    const float ad  = a_d[d * NHEAD + hh];
    const ushort4* __restrict__ Hc = (const ushort4*)H16;

    int j0 = rowptr[d], j1 = rowptr[d + 1];
    float4 acc = make_float4(0.f, 0.f, 0.f, 0.f);
    float den = 1e-16f;
    int j = j0;
    for (; j + 3 < j1; j += 4) {
        int s0 = col[j], s1 = col[j+1], s2 = col[j+2], s3 = col[j+3];
        float v0 = a_s[s0 * NHEAD + hh] + ad;
        float v1 = a_s[s1 * NHEAD + hh] + ad;
        float v2 = a_s[s2 * NHEAD + hh] + ad;
        float v3 = a_s[s3 * NHEAD + hh] + ad;
        ushort4 u0 = Hc[(size_t)s0 * 24 + lane];
        ushort4 u1 = Hc[(size_t)s1 * 24 + lane];
        ushort4 u2 = Hc[(size_t)s2 * 24 + lane];
        ushort4 u3 = Hc[(size_t)s3 * 24 + lane];
        v0 = v0 > 0.f ? v0 : 0.2f * v0;
        v1 = v1 > 0.f ? v1 : 0.2f * v1;
        v2 = v2 > 0.f ? v2 : 0.2f * v2;
        v3 = v3 > 0.f ? v3 : 0.2f * v3;
        float e0 = __expf(v0), e1 = __expf(v1), e2 = __expf(v2), e3 = __expf(v3);
        den += e0 + e1 + e2 + e3;
        float4 h0 = bf4_to_f4(u0), h1 = bf4_to_f4(u1);
        float4 h2 = bf4_to_f4(u2), h3 = bf4_to_f4(u3);
        acc.x = fmaf(e0, h0.x, acc.x); acc.y = fmaf(e0, h0.y, acc.y);
        acc.z = fmaf(e0, h0.z, acc.z); acc.w = fmaf(e0, h0.w, acc.w);
        acc.x = fmaf(e1, h1.x, acc.x); acc.y = fmaf(e1, h1.y, acc.y);
        acc.z = fmaf(e1, h1.z, acc.z); acc.w = fmaf(e1, h1.w, acc.w);
        acc.x = fmaf(e2, h2.x, acc.x); acc.y = fmaf(e2, h2.y, acc.y);
        acc.z = fmaf(e2, h2.z, acc.z); acc.w = fmaf(e2, h2.w, acc.w);
        acc.x = fmaf(e3, h3.x, acc.x); acc.y = fmaf(e3, h3.y, acc.y);
        acc.z = fmaf(e3, h3.z, acc.z); acc.w = fmaf(e3, h3.w, acc.w);
    }
    for (; j < j1; ++j) {
        int s = col[j];
        float v = a_s[s * NHEAD + hh] + ad;
        v = v > 0.f ? v : 0.2f * v;
        float ex = __expf(v);
        den += ex;
        float4 hv = bf4_to_f4(Hc[(size_t)s * 24 + lane]);
        acc.x = fmaf(ex, hv.x, acc.x); acc.y = fmaf(ex, hv.y, acc.y);
        acc.z = fmaf(ex, hv.z, acc.z); acc.w = fmaf(ex, hv.w, acc.w);
    }
    float inv = 1.0f / den;
    float4 bv = ((const float4*)bias)[lane];
    float4 o;
    o.x = fmaf(acc.x, inv, bv.x); o.y = fmaf(acc.y, inv, bv.y);
    o.z = fmaf(acc.z, inv, bv.z); o.w = fmaf(acc.w, inv, bv.w);
    o.x = o.x > 0.f ? o.x : 0.f;  o.y = o.y > 0.f ? o.y : 0.f;
    o.z = o.z > 0.f ? o.z : 0.f;  o.w = o.w > 0.f ? o.w : 0.f;
    ((float4*)out)[(size_t)d * 24 + lane] = o;
}

extern "C" void kernel_launch(void* const* d_in, const int* in_sizes, int n_in,
                              void* d_out, int out_size, void* d_ws, size_t ws_size,
                              hipStream_t stream) {
    const float* x   = (const float*)d_in[0];
    const int*   ei  = (const int*)d_in[1];
    const float* W1  = (const float*)d_in[2];
    const float* as1 = (const float*)d_in[3];
    const float* ad1 = (const float*)d_in[4];
    const float* b1  = (const float*)d_in[5];
    const float* W2  = (const float*)d_in[6];
    const float* as2 = (const float*)d_in[7];
    const float* ad2 = (const float*)d_in[8];
    const float* b2  = (const float*)d_in[9];

    const int N    = in_sizes[0] / 128;   // 50000
    const int E0   = in_sizes[1] / 2;     // 800000
    const int Etot = E0 + N;
    const int* srci = ei;
    const int* dsti = ei + E0;
    const int nbins = (N + 63) >> 6;      // 782
    const int M2    = nbins * NBLK;       // 100096

    // -------- workspace layout --------
    char* wsb = (char*)d_ws;
    unsigned short* H16 = (unsigned short*)wsb;  wsb += (size_t)N * DMODEL * 2;
    float* H1   = (float*)wsb;            wsb += (size_t)N * DMODEL * 4;
    float* AS   = (float*)wsb;            wsb += (size_t)N * NHEAD * 4;
    float* AD   = (float*)wsb;            wsb += (size_t)N * NHEAD * 4;
    int* HIST2D = (int*)wsb;              wsb += (size_t)M2 * 4;
    int* SC2D   = (int*)wsb;              wsb += (size_t)(M2 + 1) * 4;
    int* DEG    = (int*)wsb;              wsb += (size_t)N * 4;
    int* ROWPTR = (int*)wsb;              wsb += (size_t)(N + 1) * 4;
    int* BSUM   = (int*)wsb;              wsb += 256 * 4;
    int* COL    = (int*)wsb;              wsb += (size_t)Etot * 4;
    unsigned int* REC = (unsigned int*)wsb; wsb += (size_t)Etot * 4;
    float* OUT  = (float*)d_out;

    const int nb2       = (M2 + 1023) / 1024;   // 98
    const int nb_scan   = (N + 1023) / 1024;    // 49
    const int gemm_grid = (N + 63) / 64;        // 782
    const int e2_grid   = (N + 15) / 16;

    // -------- CSR build: counting sort, zero global atomics --------
    hist2d_kernel<<<NBLK, 1024, 0, stream>>>(dsti, HIST2D, E0, Etot, nbins);
    scan_block_kernel<<<nb2, 1024, 0, stream>>>(HIST2D, SC2D, BSUM, M2);
    scan_bsum_kernel<<<1, 64, 0, stream>>>(BSUM, nb2);
    scan_add_kernel<<<(M2 + 255) / 256, 256, 0, stream>>>(SC2D, BSUM, M2, Etot);
    place_kernel<<<NBLK, 1024, 0, stream>>>(srci, dsti, SC2D, REC, E0, Etot);
    bucketDeg_kernel<<<nbins, 256, 0, stream>>>(SC2D, REC, DEG, N);
    scan_block_kernel<<<nb_scan, 1024, 0, stream>>>(DEG, ROWPTR, BSUM, N);
    scan_bsum_kernel<<<1, 64, 0, stream>>>(BSUM, nb_scan);
    scan_add_kernel<<<(N + 255) / 256, 256, 0, stream>>>(ROWPTR, BSUM, N, Etot);
    bucketC_kernel<<<nbins, 256, 0, stream>>>(SC2D, REC, ROWPTR, COL);

    // -------- layer 1 --------
    gemm_scalar_att<128><<<gemm_grid, 256, 0, stream>>>(x, W1, as1, ad1, H16, AS, AD, N);
    edge2_vec_kernel<<<e2_grid, 384, 0, stream>>>(ROWPTR, COL, H16, AS, AD, b1, H1, N);

    // -------- layer 2 --------
    gemm_scalar_att<96><<<gemm_grid, 256, 0, stream>>>(H1, W2, as2, ad2, H16, AS, AD, N);
    edge2_vec_kernel<<<e2_grid, 384, 0, stream>>>(ROWPTR, COL, H16, AS, AD, b2, OUT, N);
}